// Round 16
// baseline (178.538 us; speedup 1.0000x reference)
//
#include <hip/hip_runtime.h>
#include <hip/hip_cooperative_groups.h>
#include <hip/hip_bf16.h>

namespace cg = cooperative_groups;

#define NDEPTH 59
#define NC 64
#define NCHTOT 123
#define NB 4
#define NCAM 6
#define FH 16
#define FW 44
#define W2N 2                   // w-columns per block
#define NWG (FW/W2N)            // 22 w-groups
#define GXN 200
#define GYN 200
#define NBLK (NB*NCAM*NWG)      // 528 blocks
#define NTHR 512
#define POOLED_N ((size_t)NB*GXN*GYN*NC)

// Compute comb = R @ inv(K) and trans for one (b,n). Lane-uniform helper.
__device__ __forceinline__ void compute_comb(const float* __restrict__ K,
                                             const float* __restrict__ E,
                                             float M[9], float T[3]) {
  float a00=K[0],a01=K[1],a02=K[2];
  float a10=K[3],a11=K[4],a12=K[5];
  float a20=K[6],a21=K[7],a22=K[8];
  float det = a00*(a11*a22-a12*a21) - a01*(a10*a22-a12*a20) + a02*(a10*a21-a11*a20);
  float inv[9];
  inv[0]=(a11*a22-a12*a21)/det; inv[1]=(a02*a21-a01*a22)/det; inv[2]=(a01*a12-a02*a11)/det;
  inv[3]=(a12*a20-a10*a22)/det; inv[4]=(a00*a22-a02*a20)/det; inv[5]=(a02*a10-a00*a12)/det;
  inv[6]=(a10*a21-a11*a20)/det; inv[7]=(a01*a20-a00*a21)/det; inv[8]=(a00*a11-a01*a10)/det;
  for (int i=0;i<3;i++){
    for (int j=0;j<3;j++){
      float s=0.f;
      for (int k=0;k<3;k++) s += E[i*4+k]*inv[k*3+j];
      M[i*3+j]=s;
    }
    T[i]=E[i*4+3];
  }
}

// Wide zero (fallback path only).
__global__ __launch_bounds__(256) void zero_buf(float4* __restrict__ p, int n4) {
  int stride = gridDim.x * 256;
  for (int i = blockIdx.x*256 + threadIdx.x; i < n4; i += stride)
    p[i] = make_float4(0.f, 0.f, 0.f, 0.f);
}

// Fused zero + scatter + transpose, one cooperative launch. Phase bodies
// (staging/softmax/GEMM/atomic/transpose) are byte-identical to the R15
// passing 3-kernel version; grid.sync() replaces the kernel boundaries so
// the zero's write-drain overlaps staging+softmax, and launch overhead for
// 2 kernels disappears. 528 blocks x 512 thr, 26 KB LDS -> 4 blocks/CU
// co-resident (cooperative capacity OK).
__global__ __launch_bounds__(NTHR) void lss_fused(
    const float* __restrict__ cam, const float* __restrict__ intr,
    const float* __restrict__ extr, float* __restrict__ pooled,
    float* __restrict__ out) {
  __shared__ union U {
    struct { float raw[W2N][FH][124]; float A[W2N][64][20]; } s;
    float tile[64][65];
    __device__ U() {}
  } u;
  float (&raw)[W2N][FH][124] = u.s.raw;
  float (&A)[W2N][64][20]    = u.s.A;

  cg::grid_group grid = cg::this_grid();

  int bx  = blockIdx.x;
  int wg  = bx % NWG;
  int nbi = bx / NWG;                 // b*NCAM + n
  int b   = nbi / NCAM;
  int w0  = wg * W2N;
  int tid = threadIdx.x;

  float M[9], T[3];
  compute_comb(intr + nbi*9, extr + nbi*16, M, T);

  // ---- phase A1: stage 123ch x 16h x 2w as float2 over w ----
  const float* base = cam + ((size_t)nbi*NCHTOT)*(FH*FW) + w0;
  for (int idx = tid; idx < NCHTOT*FH; idx += NTHR) {
    int h = idx / NCHTOT, ch = idx - h*NCHTOT;
    float2 v = *(const float2*)(base + ch*(FH*FW) + h*FW);
    raw[0][h][ch]=v.x; raw[1][h][ch]=v.y;
  }

  // ---- phase A2: grid-stride zero of pooled (overlaps staging drain) ----
  {
    float4* p4 = (float4*)pooled;
    int n4 = (int)(POOLED_N/4);
    int gstride = gridDim.x * NTHR;
    for (int idx = blockIdx.x*NTHR + tid; idx < n4; idx += gstride)
      p4[idx] = make_float4(0.f, 0.f, 0.f, 0.f);
  }
  __syncthreads();

  // ---- phase A3: per-(w2,h) softmax over depth + iz mask -> A[w2][d][h] ----
  {
    int w2 = tid >> 8, h = (tid >> 4) & 15, l = tid & 15;
    int w = w0 + w2;
    float fx = (w == FW-1) ? 703.0f : (float)((double)w * (703.0/43.0));
    float fy = 17.0f * (float)h;
    float v0 = raw[w2][h][l];
    float v1 = raw[w2][h][l+16];
    float v2 = raw[w2][h][l+32];
    float v3 = (l+48 < NDEPTH) ? raw[w2][h][l+48] : -INFINITY;
    float m = fmaxf(fmaxf(v0,v1), fmaxf(v2,v3));
    #pragma unroll
    for (int off=8; off; off>>=1) m = fmaxf(m, __shfl_xor(m, off));
    float e[4];
    e[0]=expf(v0-m); e[1]=expf(v1-m); e[2]=expf(v2-m);
    e[3]=(l+48 < NDEPTH) ? expf(v3-m) : 0.f;
    float s = e[0]+e[1]+e[2]+e[3];
    #pragma unroll
    for (int off=8; off; off>>=1) s += __shfl_xor(s, off);
    #pragma unroll
    for (int k=0;k<4;k++){
      int d = l + 16*k;
      if (d < NDEPTH) {
        float fd = (float)(d+1);
        float px = fx*fd, py = fy*fd, pz = fd;
        float gz = M[6]*px + M[7]*py + M[8]*pz + T[2];
        int iz = (int)((gz + 10.0f) / 20.0f);
        A[w2][d][h] = (iz == 0) ? (e[k]/s) : 0.f;
      }
    }
  }

  grid.sync();   // all zeroing complete chip-wide before any atomic

  // ---- phase B: wave g in [0,8) -> (w2=g>>2, d=g&3 mod 4). GEMM + atomic ----
  {
    int g = tid >> 6, c = tid & 63;
    int w2 = g >> 2, sub = g & 3;
    int w = w0 + w2;
    float fx = (w == FW-1) ? 703.0f : (float)((double)w * (703.0/43.0));
    float F[16];
    #pragma unroll
    for (int h=0; h<16; h++) F[h] = raw[w2][h][NDEPTH + c];
    for (int d = sub; d < NDEPTH; d += 4) {
      float fd = (float)(d+1);
      float px = fx*fd, py = 0.0f, pz = fd;   // M[1],M[4]==0.0 exactly
      float gx = M[0]*px + M[1]*py + M[2]*pz + T[0];
      float gy = M[3]*px + M[4]*py + M[5]*pz + T[1];
      int ix = (int)((gx + 50.0f) / 0.5f);
      int iy = (int)((gy + 50.0f) / 0.5f);
      if (ix>=0 && ix<GXN && iy>=0 && iy<GYN) {
        float acc = 0.f;
        #pragma unroll
        for (int h=0; h<16; h++) acc = fmaf(A[w2][d][h], F[h], acc);
        size_t o = ((((size_t)b*GXN + (GXN-1-ix))*GYN + (GYN-1-iy))*NC + c);
        atomicAdd(pooled + o, acc);   // fire-and-forget, 4-line pattern
      }
    }
  }

  grid.sync();   // all atomics visible (device-scope) before transpose

  // ---- phase C: grid-stride transpose pooled[b][i][j][c] -> out[b][c][i][j] ----
  for (int t = blockIdx.x; t < NB*GXN*4; t += gridDim.x) {
    int tb  = t / (GXN*4);
    int rem = t % (GXN*4);
    int i   = rem >> 2;
    int j0  = (rem & 3) * 64;
    const float* src = pooled + (((size_t)tb*GXN + i)*GYN)*NC;
    #pragma unroll
    for (int k=0;k<8;k++){
      int idx = tid + k*NTHR;
      int c = idx & 63, jj = idx >> 6;
      int j = j0 + jj;
      if (j < GYN) u.tile[jj][c] = src[(size_t)j*NC + c];
    }
    __syncthreads();
    #pragma unroll
    for (int k=0;k<8;k++){
      int idx = tid + k*NTHR;
      int jj = idx & 63, c = idx >> 6;
      int j = j0 + jj;
      if (j < GYN) out[(((size_t)(tb*NC + c)*GXN) + i)*GYN + j] = u.tile[jj][c];
    }
    __syncthreads();
  }
}

// ---- fallback 3-kernel path (also used if cooperative launch fails) ----
template<int DIRECT>
__global__ __launch_bounds__(512) void lss_scatter4(
    const float* __restrict__ cam, const float* __restrict__ intr,
    const float* __restrict__ extr, float* __restrict__ dst) {
  __shared__ float raw[W2N][FH][124];
  __shared__ float A[W2N][64][20];
  int bx  = blockIdx.x;
  int wg  = bx % NWG;
  int nbi = bx / NWG;
  int b   = nbi / NCAM;
  int w0  = wg * W2N;
  int tid = threadIdx.x;
  float M[9], T[3];
  compute_comb(intr + nbi*9, extr + nbi*16, M, T);
  const float* base = cam + ((size_t)nbi*NCHTOT)*(FH*FW) + w0;
  for (int idx = tid; idx < NCHTOT*FH; idx += 512) {
    int h = idx / NCHTOT, ch = idx - h*NCHTOT;
    float2 v = *(const float2*)(base + ch*(FH*FW) + h*FW);
    raw[0][h][ch]=v.x; raw[1][h][ch]=v.y;
  }
  __syncthreads();
  {
    int w2 = tid >> 8, h = (tid >> 4) & 15, l = tid & 15;
    int w = w0 + w2;
    float fx = (w == FW-1) ? 703.0f : (float)((double)w * (703.0/43.0));
    float fy = 17.0f * (float)h;
    float v0 = raw[w2][h][l], v1 = raw[w2][h][l+16], v2 = raw[w2][h][l+32];
    float v3 = (l+48 < NDEPTH) ? raw[w2][h][l+48] : -INFINITY;
    float m = fmaxf(fmaxf(v0,v1), fmaxf(v2,v3));
    #pragma unroll
    for (int off=8; off; off>>=1) m = fmaxf(m, __shfl_xor(m, off));
    float e[4];
    e[0]=expf(v0-m); e[1]=expf(v1-m); e[2]=expf(v2-m);
    e[3]=(l+48 < NDEPTH) ? expf(v3-m) : 0.f;
    float s = e[0]+e[1]+e[2]+e[3];
    #pragma unroll
    for (int off=8; off; off>>=1) s += __shfl_xor(s, off);
    #pragma unroll
    for (int k=0;k<4;k++){
      int d = l + 16*k;
      if (d < NDEPTH) {
        float fd = (float)(d+1);
        float px = fx*fd, py = fy*fd, pz = fd;
        float gz = M[6]*px + M[7]*py + M[8]*pz + T[2];
        int iz = (int)((gz + 10.0f) / 20.0f);
        A[w2][d][h] = (iz == 0) ? (e[k]/s) : 0.f;
      }
    }
  }
  __syncthreads();
  {
    int g = tid >> 6, c = tid & 63;
    int w2 = g >> 2, sub = g & 3;
    int w = w0 + w2;
    float fx = (w == FW-1) ? 703.0f : (float)((double)w * (703.0/43.0));
    float F[16];
    #pragma unroll
    for (int h=0; h<16; h++) F[h] = raw[w2][h][NDEPTH + c];
    for (int d = sub; d < NDEPTH; d += 4) {
      float fd = (float)(d+1);
      float px = fx*fd, py = 0.0f, pz = fd;
      float gx = M[0]*px + M[1]*py + M[2]*pz + T[0];
      float gy = M[3]*px + M[4]*py + M[5]*pz + T[1];
      int ix = (int)((gx + 50.0f) / 0.5f);
      int iy = (int)((gy + 50.0f) / 0.5f);
      if (ix>=0 && ix<GXN && iy>=0 && iy<GYN) {
        float acc = 0.f;
        #pragma unroll
        for (int h=0; h<16; h++) acc = fmaf(A[w2][d][h], F[h], acc);
        if (DIRECT) {
          size_t o = (((size_t)(b*NC+c)*GXN + (GXN-1-ix))*GYN + (GYN-1-iy));
          atomicAdd(dst + o, acc);
        } else {
          size_t o = ((((size_t)b*GXN + (GXN-1-ix))*GYN + (GYN-1-iy))*NC + c);
          atomicAdd(dst + o, acc);
        }
      }
    }
  }
}

__global__ __launch_bounds__(256) void lss_transpose(const float* __restrict__ pooled,
                                                     float* __restrict__ out) {
  __shared__ float tile[64][65];
  int b  = blockIdx.z;
  int i  = blockIdx.y;
  int j0 = blockIdx.x * 64;
  const float* src = pooled + (((size_t)b*GXN + i)*GYN)*NC;
  #pragma unroll
  for (int k=0;k<16;k++){
    int idx = threadIdx.x + k*256;
    int c = idx & 63, jj = idx >> 6;
    int j = j0 + jj;
    if (j < GYN) tile[jj][c] = src[(size_t)j*NC + c];
  }
  __syncthreads();
  #pragma unroll
  for (int k=0;k<16;k++){
    int idx = threadIdx.x + k*256;
    int jj = idx & 63, c = idx >> 6;
    int j = j0 + jj;
    if (j < GYN) out[(((size_t)(b*NC + c)*GXN) + i)*GYN + j] = tile[jj][c];
  }
}

extern "C" void kernel_launch(void* const* d_in, const int* in_sizes, int n_in,
                              void* d_out, int out_size, void* d_ws, size_t ws_size,
                              hipStream_t stream) {
  const float* cam  = (const float*)d_in[0];
  const float* intr = (const float*)d_in[1];
  const float* extr = (const float*)d_in[2];
  float* out = (float*)d_out;

  size_t pooled_bytes = POOLED_N*sizeof(float);  // ~41 MB
  if (ws_size >= pooled_bytes) {
    float* pooled = (float*)d_ws;
    void* args[] = { (void*)&cam, (void*)&intr, (void*)&extr,
                     (void*)&pooled, (void*)&out };
    hipError_t err = hipLaunchCooperativeKernel(
        (const void*)lss_fused, dim3(NBLK), dim3(NTHR), args, 0, stream);
    if (err != hipSuccess) {
      // fallback: proven 3-kernel path (R15)
      zero_buf<<<2048, 256, 0, stream>>>((float4*)pooled, (int)(POOLED_N/4));
      lss_scatter4<0><<<NBLK, 512, 0, stream>>>(cam, intr, extr, pooled);
      lss_transpose<<<dim3((GYN+63)/64, GXN, NB), 256, 0, stream>>>(pooled, out);
    }
  } else {
    zero_buf<<<2048, 256, 0, stream>>>((float4*)out, out_size/4);
    lss_scatter4<1><<<NBLK, 512, 0, stream>>>(cam, intr, extr, out);
  }
}

// Round 17
// 59.575 us; speedup vs baseline: 2.9969x; 2.9969x over previous
//
#include <hip/hip_runtime.h>
#include <hip/hip_bf16.h>

#define NDEPTH 59
#define NC 64
#define NCHTOT 123
#define NB 4
#define NCAM 6
#define FH 16
#define FW 44
#define W2N 2                   // w-columns per block
#define NWG (FW/W2N)            // 22 w-groups
#define GXN 200
#define GYN 200

// Compute comb = R @ inv(K) and trans for one (b,n). Lane-uniform helper.
__device__ __forceinline__ void compute_comb(const float* __restrict__ K,
                                             const float* __restrict__ E,
                                             float M[9], float T[3]) {
  float a00=K[0],a01=K[1],a02=K[2];
  float a10=K[3],a11=K[4],a12=K[5];
  float a20=K[6],a21=K[7],a22=K[8];
  float det = a00*(a11*a22-a12*a21) - a01*(a10*a22-a12*a20) + a02*(a10*a21-a11*a20);
  float inv[9];
  inv[0]=(a11*a22-a12*a21)/det; inv[1]=(a02*a21-a01*a22)/det; inv[2]=(a01*a12-a02*a11)/det;
  inv[3]=(a12*a20-a10*a22)/det; inv[4]=(a00*a22-a02*a20)/det; inv[5]=(a02*a10-a00*a12)/det;
  inv[6]=(a10*a21-a11*a20)/det; inv[7]=(a01*a20-a00*a21)/det; inv[8]=(a00*a11-a01*a10)/det;
  for (int i=0;i<3;i++){
    for (int j=0;j<3;j++){
      float s=0.f;
      for (int k=0;k<3;k++) s += E[i*4+k]*inv[k*3+j];
      M[i*3+j]=s;
    }
    T[i]=E[i*4+3];
  }
}

// Wide zero (write-BW bound).
__global__ __launch_bounds__(256) void zero_buf(float4* __restrict__ p, int n4) {
  int stride = gridDim.x * 256;
  for (int i = blockIdx.x*256 + threadIdx.x; i < n4; i += stride)
    p[i] = make_float4(0.f, 0.f, 0.f, 0.f);
}

// One 512-thread block per (b,n, 2 w-columns) -- R15's passing kernel,
// byte-identical. Scatter into pooled NHWC (R12 lesson: 4-consecutive-line
// atomic pattern; NCHW 64-line is ~7x worse). Geometry expression text
// identical to what has passed since R2.
template<int DIRECT>
__global__ __launch_bounds__(512) void lss_scatter4(
    const float* __restrict__ cam, const float* __restrict__ intr,
    const float* __restrict__ extr, float* __restrict__ dst) {
  __shared__ float raw[W2N][FH][124];   // [w2][h][ch]: 59 logits + 64 feats
  __shared__ float A[W2N][64][20];      // [w2][d][h]: masked softmax weight

  int bx  = blockIdx.x;
  int wg  = bx % NWG;
  int nbi = bx / NWG;                 // b*NCAM + n
  int b   = nbi / NCAM;
  int w0  = wg * W2N;
  int tid = threadIdx.x;

  float M[9], T[3];
  compute_comb(intr + nbi*9, extr + nbi*16, M, T);

  // phase 1: stage 123ch x 16h x 2w as float2 over w (all offsets even -> aligned)
  const float* base = cam + ((size_t)nbi*NCHTOT)*(FH*FW) + w0;
  for (int idx = tid; idx < NCHTOT*FH; idx += 512) {
    int h = idx / NCHTOT, ch = idx - h*NCHTOT;
    float2 v = *(const float2*)(base + ch*(FH*FW) + h*FW);
    raw[0][h][ch]=v.x; raw[1][h][ch]=v.y;
  }
  __syncthreads();

  // phase 2: per-(w2,h) softmax over depth + iz mask -> A[w2][d][h]
  {
    int w2 = tid >> 8, h = (tid >> 4) & 15, l = tid & 15;
    int w = w0 + w2;
    float fx = (w == FW-1) ? 703.0f : (float)((double)w * (703.0/43.0));
    float fy = 17.0f * (float)h;
    float v0 = raw[w2][h][l];
    float v1 = raw[w2][h][l+16];
    float v2 = raw[w2][h][l+32];
    float v3 = (l+48 < NDEPTH) ? raw[w2][h][l+48] : -INFINITY;
    float m = fmaxf(fmaxf(v0,v1), fmaxf(v2,v3));
    #pragma unroll
    for (int off=8; off; off>>=1) m = fmaxf(m, __shfl_xor(m, off));
    float e[4];
    e[0]=expf(v0-m); e[1]=expf(v1-m); e[2]=expf(v2-m);
    e[3]=(l+48 < NDEPTH) ? expf(v3-m) : 0.f;
    float s = e[0]+e[1]+e[2]+e[3];
    #pragma unroll
    for (int off=8; off; off>>=1) s += __shfl_xor(s, off);
    #pragma unroll
    for (int k=0;k<4;k++){
      int d = l + 16*k;
      if (d < NDEPTH) {
        float fd = (float)(d+1);
        float px = fx*fd, py = fy*fd, pz = fd;
        float gz = M[6]*px + M[7]*py + M[8]*pz + T[2];
        int iz = (int)((gz + 10.0f) / 20.0f);
        A[w2][d][h] = (iz == 0) ? (e[k]/s) : 0.f;
      }
    }
  }
  __syncthreads();

  // phase 3: wave g in [0,8) -> (w2 = g>>2, d = g&3 mod 4). GEMM + NHWC atomic.
  {
    int g = tid >> 6, c = tid & 63;
    int w2 = g >> 2, sub = g & 3;
    int w = w0 + w2;
    float fx = (w == FW-1) ? 703.0f : (float)((double)w * (703.0/43.0));
    float F[16];
    #pragma unroll
    for (int h=0; h<16; h++) F[h] = raw[w2][h][NDEPTH + c];
    for (int d = sub; d < NDEPTH; d += 4) {
      float fd = (float)(d+1);
      float px = fx*fd, py = 0.0f, pz = fd;   // M[1],M[4]==0.0 exactly
      float gx = M[0]*px + M[1]*py + M[2]*pz + T[0];
      float gy = M[3]*px + M[4]*py + M[5]*pz + T[1];
      int ix = (int)((gx + 50.0f) / 0.5f);
      int iy = (int)((gy + 50.0f) / 0.5f);
      if (ix>=0 && ix<GXN && iy>=0 && iy<GYN) {
        float acc = 0.f;
        #pragma unroll
        for (int h=0; h<16; h++) acc = fmaf(A[w2][d][h], F[h], acc);
        if (DIRECT) {
          size_t o = (((size_t)(b*NC+c)*GXN + (GXN-1-ix))*GYN + (GYN-1-iy));
          atomicAdd(dst + o, acc);
        } else {
          size_t o = ((((size_t)b*GXN + (GXN-1-ix))*GYN + (GYN-1-iy))*NC + c);
          atomicAdd(dst + o, acc);   // fire-and-forget, 4-line pattern
        }
      }
    }
  }
}

// pooled[b][i][j][c] -> out[b][c][i][j]. Load side as R15; store side
// vectorized to float4 along j (G13): 4x fewer store instrs, 16B/lane.
// LDS gather tile[4jv+r][c]: bank = (4jv+r+c) mod 32 (65==1 mod 32) -> exact
// 2-way aliasing = free (m136). GYN=200 % 4 == 0 -> stores aligned.
__global__ __launch_bounds__(256) void lss_transpose(const float* __restrict__ pooled,
                                                     float* __restrict__ out) {
  __shared__ float tile[64][65];
  int b  = blockIdx.z;
  int i  = blockIdx.y;
  int j0 = blockIdx.x * 64;
  const float* src = pooled + (((size_t)b*GXN + i)*GYN)*NC;
  #pragma unroll
  for (int k=0;k<16;k++){
    int idx = threadIdx.x + k*256;
    int c = idx & 63, jj = idx >> 6;
    int j = j0 + jj;
    if (j < GYN) tile[jj][c] = src[(size_t)j*NC + c];
  }
  __syncthreads();
  #pragma unroll
  for (int k=0;k<4;k++){
    int idx = threadIdx.x + k*256;
    int jv = idx & 15, c = idx >> 4;   // jv: float4 index within 64-j tile
    int j = j0 + jv*4;
    if (j + 3 < GYN) {
      float4 v = make_float4(tile[jv*4+0][c], tile[jv*4+1][c],
                             tile[jv*4+2][c], tile[jv*4+3][c]);
      *(float4*)(&out[(((size_t)(b*NC + c)*GXN) + i)*GYN + j]) = v;
    }
  }
}

extern "C" void kernel_launch(void* const* d_in, const int* in_sizes, int n_in,
                              void* d_out, int out_size, void* d_ws, size_t ws_size,
                              hipStream_t stream) {
  const float* cam  = (const float*)d_in[0];
  const float* intr = (const float*)d_in[1];
  const float* extr = (const float*)d_in[2];
  float* out = (float*)d_out;

  size_t pooled_elems = (size_t)NB*GXN*GYN*NC;           // ~41 MB
  size_t pooled_bytes = pooled_elems*sizeof(float);
  if (ws_size >= pooled_bytes) {
    float* pooled = (float*)d_ws;
    zero_buf<<<2048, 256, 0, stream>>>((float4*)pooled, (int)(pooled_elems/4));
    lss_scatter4<0><<<NB*NCAM*NWG, 512, 0, stream>>>(cam, intr, extr, pooled);
    lss_transpose<<<dim3((GYN+63)/64, GXN, NB), 256, 0, stream>>>(pooled, out);
  } else {
    zero_buf<<<2048, 256, 0, stream>>>((float4*)out, out_size/4);
    lss_scatter4<1><<<NB*NCAM*NWG, 512, 0, stream>>>(cam, intr, extr, out);
  }
}